// Round 1
// baseline (1265.902 us; speedup 1.0000x reference)
//
#include <hip/hip_runtime.h>
#include <math.h>

#define KNB 16
#define NPTS 4096
#define NB 2
#define CH 256
#define INC 515
#define PITCH 20
#define BNEPS 1e-5f
#define SLOPE 0.1f

__device__ __forceinline__ float leaky(float x) { return x >= 0.f ? x : SLOPE * x; }

// ---------------- transpose feature [B,C,N] -> [B,N,C] ----------------
__global__ __launch_bounds__(256) void transpose_feat(const float* __restrict__ in,
                                                      float* __restrict__ out) {
  int bn = blockIdx.x;  // b*NPTS + n
  int b = bn >> 12, n = bn & 4095;
  int c = threadIdx.x;
  out[(size_t)bn * CH + c] = in[((size_t)(b * CH + c)) * NPTS + n];
}

// ---------------- transpose weight [O,Cc] -> [Cc,O] ----------------
__global__ __launch_bounds__(256) void transpose_w(const float* __restrict__ in,
                                                   float* __restrict__ out, int O, int Cc) {
  int id = blockIdx.x * blockDim.x + threadIdx.x;
  if (id >= O * Cc) return;
  int o = id % O, c = id / O;
  out[c * O + o] = in[o * Cc + c];
}

// ---------------- KNN: one wave per query, top-16 ----------------
__global__ __launch_bounds__(256) void knn_kernel(const float* __restrict__ q,
                                                  const float* __restrict__ p,
                                                  int* __restrict__ idx_out) {
  int gw = (blockIdx.x * 256 + threadIdx.x) >> 6;
  int lane = threadIdx.x & 63;
  if (gw >= NB * NPTS) return;
  int b = gw >> 12, n = gw & 4095;
  const float* qb = q + (size_t)b * 3 * NPTS;
  const float* pb = p + (size_t)b * 3 * NPTS;
  float qx = qb[n], qy = qb[NPTS + n], qz = qb[2 * NPTS + n];
  float qn = __fadd_rn(__fadd_rn(__fmul_rn(qx, qx), __fmul_rn(qy, qy)), __fmul_rn(qz, qz));
  float ld[KNB];
  int li[KNB];
#pragma unroll
  for (int s = 0; s < KNB; ++s) { ld[s] = INFINITY; li[s] = 0x7fffffff; }
  for (int j = lane; j < NPTS; j += 64) {
    float px = pb[j], py = pb[NPTS + j], pz = pb[2 * NPTS + j];
    float dot = __fadd_rn(__fadd_rn(__fmul_rn(qx, px), __fmul_rn(qy, py)), __fmul_rn(qz, pz));
    float pn = __fadd_rn(__fadd_rn(__fmul_rn(px, px), __fmul_rn(py, py)), __fmul_rn(pz, pz));
    float d = __fadd_rn(__fsub_rn(qn, __fmul_rn(2.f, dot)), pn);
    if (d < ld[KNB - 1]) {
      ld[KNB - 1] = d;
      li[KNB - 1] = j;
#pragma unroll
      for (int s = KNB - 1; s > 0; --s) {
        bool sw = ld[s] < ld[s - 1];
        if (sw) {
          float td = ld[s]; ld[s] = ld[s - 1]; ld[s - 1] = td;
          int ti = li[s]; li[s] = li[s - 1]; li[s - 1] = ti;
        }
      }
    }
  }
  // 16-round cross-lane merge (lexicographic min on (dist, idx) -> matches top_k stability)
  int* op = idx_out + (size_t)gw * KNB;
  for (int r = 0; r < KNB; ++r) {
    float bd = ld[0];
    int bi = li[0];
#pragma unroll
    for (int off = 1; off < 64; off <<= 1) {
      float od = __shfl_xor(bd, off);
      int oi = __shfl_xor(bi, off);
      if (od < bd || (od == bd && oi < bi)) { bd = od; bi = oi; }
    }
    if (lane == 0) op[r] = bi;
    if (li[0] == bi) {  // pop winner (candidate indices are unique)
#pragma unroll
      for (int s = 0; s < KNB - 1; ++s) { ld[s] = ld[s + 1]; li[s] = li[s + 1]; }
      ld[KNB - 1] = INFINITY;
      li[KNB - 1] = 0x7fffffff;
    }
  }
}

#define FMA16(XBASE)                                                     \
  do {                                                                   \
    const float4* x4_ = (const float4*)&xs[(XBASE)];                     \
    float4 a_ = x4_[0], b_ = x4_[1], c_ = x4_[2], d_ = x4_[3];           \
    acc[0] = fmaf(a_.x, w, acc[0]);  acc[1] = fmaf(a_.y, w, acc[1]);     \
    acc[2] = fmaf(a_.z, w, acc[2]);  acc[3] = fmaf(a_.w, w, acc[3]);     \
    acc[4] = fmaf(b_.x, w, acc[4]);  acc[5] = fmaf(b_.y, w, acc[5]);     \
    acc[6] = fmaf(b_.z, w, acc[6]);  acc[7] = fmaf(b_.w, w, acc[7]);     \
    acc[8] = fmaf(c_.x, w, acc[8]);  acc[9] = fmaf(c_.y, w, acc[9]);     \
    acc[10] = fmaf(c_.z, w, acc[10]); acc[11] = fmaf(c_.w, w, acc[11]);  \
    acc[12] = fmaf(d_.x, w, acc[12]); acc[13] = fmaf(d_.y, w, acc[13]);  \
    acc[14] = fmaf(d_.z, w, acc[14]); acc[15] = fmaf(d_.w, w, acc[15]);  \
  } while (0)

// ---------------- stage 1: build x, 3-layer MLP, weightnet1, K-reduce ----------------
__global__ __launch_bounds__(256) void stage1_kernel(
    const float* __restrict__ f1t, const float* __restrict__ f2t,
    const float* __restrict__ pc1, const float* __restrict__ pc2,
    const int* __restrict__ idx1,
    const float* __restrict__ W0T, const float* __restrict__ b0,
    const float* __restrict__ W1T, const float* __restrict__ b1,
    const float* __restrict__ W2T, const float* __restrict__ b2,
    const float* __restrict__ wn_W1, const float* __restrict__ wn_b1,
    const float* __restrict__ wn_g, const float* __restrict__ wn_be,
    const float* __restrict__ wn_m, const float* __restrict__ wn_v,
    const float* __restrict__ wn_W2, const float* __restrict__ wn_b2,
    float* __restrict__ out1) {
  __shared__ float xs[INC * PITCH];
  __shared__ float h1[KNB][8];
  __shared__ int nbrs[KNB];
  int bn = blockIdx.x;
  int b = bn >> 12, n = bn & 4095;
  int t = threadIdx.x;
  if (t < KNB) nbrs[t] = idx1[(size_t)bn * KNB + t];
  float f1v = f1t[(size_t)bn * CH + t];
  __syncthreads();
  // rows [0,256): f1 broadcast across k
  {
    float4 f4 = make_float4(f1v, f1v, f1v, f1v);
    float4* xw = (float4*)&xs[t * PITCH];
    xw[0] = f4; xw[1] = f4; xw[2] = f4; xw[3] = f4;
  }
  // rows [256,512): gathered f2
#pragma unroll
  for (int k = 0; k < KNB; ++k) {
    int j = nbrs[k];
    xs[(256 + t) * PITCH + k] = f2t[((size_t)(b * NPTS) + j) * CH + t];
  }
  // rows [512,515): direction; plus weightnet hidden layer
  if (t < 128) {
    int k = t >> 3, jj = t & 7;
    int j = nbrs[k];
    const float* p1 = pc1 + (size_t)b * 3 * NPTS;
    const float* p2 = pc2 + (size_t)b * 3 * NPTS;
    float d0 = p2[j] - p1[n];
    float d1 = p2[NPTS + j] - p1[NPTS + n];
    float d2v = p2[2 * NPTS + j] - p1[2 * NPTS + n];
    if (jj < 3) xs[(512 + jj) * PITCH + k] = (jj == 0) ? d0 : ((jj == 1) ? d1 : d2v);
    float hv = d0 * wn_W1[jj * 3] + d1 * wn_W1[jj * 3 + 1] + d2v * wn_W1[jj * 3 + 2] + wn_b1[jj];
    hv = wn_g[jj] * (hv - wn_m[jj]) * (1.f / sqrtf(wn_v[jj] + BNEPS)) + wn_be[jj];
    h1[k][jj] = fmaxf(hv, 0.f);
  }
  __syncthreads();

  float acc[KNB];
  // ---- layer 0: 515 -> 256 ----
  {
    float bias = b0[t];
#pragma unroll
    for (int k = 0; k < KNB; ++k) acc[k] = bias;
    for (int c = 0; c < INC; ++c) {
      float w = W0T[c * CH + t];
      FMA16(c * PITCH);
    }
#pragma unroll
    for (int k = 0; k < KNB; ++k) acc[k] = leaky(acc[k]);
  }
  __syncthreads();
  {
    float4* xw = (float4*)&xs[t * PITCH];
    xw[0] = make_float4(acc[0], acc[1], acc[2], acc[3]);
    xw[1] = make_float4(acc[4], acc[5], acc[6], acc[7]);
    xw[2] = make_float4(acc[8], acc[9], acc[10], acc[11]);
    xw[3] = make_float4(acc[12], acc[13], acc[14], acc[15]);
  }
  __syncthreads();
  // ---- layer 1: 256 -> 256 ----
  {
    float bias = b1[t];
#pragma unroll
    for (int k = 0; k < KNB; ++k) acc[k] = bias;
    for (int c = 0; c < CH; ++c) {
      float w = W1T[c * CH + t];
      FMA16(c * PITCH);
    }
#pragma unroll
    for (int k = 0; k < KNB; ++k) acc[k] = leaky(acc[k]);
  }
  __syncthreads();
  {
    float4* xw = (float4*)&xs[t * PITCH];
    xw[0] = make_float4(acc[0], acc[1], acc[2], acc[3]);
    xw[1] = make_float4(acc[4], acc[5], acc[6], acc[7]);
    xw[2] = make_float4(acc[8], acc[9], acc[10], acc[11]);
    xw[3] = make_float4(acc[12], acc[13], acc[14], acc[15]);
  }
  __syncthreads();
  // ---- layer 2: 256 -> 256 ----
  {
    float bias = b2[t];
#pragma unroll
    for (int k = 0; k < KNB; ++k) acc[k] = bias;
    for (int c = 0; c < CH; ++c) {
      float w = W2T[c * CH + t];
      FMA16(c * PITCH);
    }
#pragma unroll
    for (int k = 0; k < KNB; ++k) acc[k] = leaky(acc[k]);
  }
  // ---- weightnet apply + K reduce (in registers) ----
  float wrow[8];
#pragma unroll
  for (int jj = 0; jj < 8; ++jj) wrow[jj] = wn_W2[t * 8 + jj];
  float wb = wn_b2[t];
  float outv = 0.f;
#pragma unroll
  for (int k = 0; k < KNB; ++k) {
    float w1 = wb;
#pragma unroll
    for (int jj = 0; jj < 8; ++jj) w1 = fmaf(h1[k][jj], wrow[jj], w1);
    outv = fmaf(w1, acc[k], outv);
  }
  out1[(size_t)bn * CH + t] = outv;
}

// ---------------- stage 2: gather out1, weightnet2, K-reduce, write [B,C,N] ----------------
__global__ __launch_bounds__(256) void stage2_kernel(
    const float* __restrict__ out1, const float* __restrict__ pc1,
    const int* __restrict__ idx2,
    const float* __restrict__ wn_W1, const float* __restrict__ wn_b1,
    const float* __restrict__ wn_g, const float* __restrict__ wn_be,
    const float* __restrict__ wn_m, const float* __restrict__ wn_v,
    const float* __restrict__ wn_W2, const float* __restrict__ wn_b2,
    float* __restrict__ outp) {
  __shared__ float h1[KNB][8];
  __shared__ int nbrs[KNB];
  int bn = blockIdx.x;
  int b = bn >> 12, n = bn & 4095;
  int t = threadIdx.x;
  if (t < KNB) nbrs[t] = idx2[(size_t)bn * KNB + t];
  __syncthreads();
  if (t < 128) {
    int k = t >> 3, jj = t & 7;
    int j = nbrs[k];
    const float* p1 = pc1 + (size_t)b * 3 * NPTS;
    float d0 = p1[j] - p1[n];
    float d1 = p1[NPTS + j] - p1[NPTS + n];
    float d2v = p1[2 * NPTS + j] - p1[2 * NPTS + n];
    float hv = d0 * wn_W1[jj * 3] + d1 * wn_W1[jj * 3 + 1] + d2v * wn_W1[jj * 3 + 2] + wn_b1[jj];
    hv = wn_g[jj] * (hv - wn_m[jj]) * (1.f / sqrtf(wn_v[jj] + BNEPS)) + wn_be[jj];
    h1[k][jj] = fmaxf(hv, 0.f);
  }
  __syncthreads();
  float wrow[8];
#pragma unroll
  for (int jj = 0; jj < 8; ++jj) wrow[jj] = wn_W2[t * 8 + jj];
  float wb = wn_b2[t];
  float outv = 0.f;
#pragma unroll
  for (int k = 0; k < KNB; ++k) {
    float w2 = wb;
#pragma unroll
    for (int jj = 0; jj < 8; ++jj) w2 = fmaf(h1[k][jj], wrow[jj], w2);
    float v = out1[((size_t)(b * NPTS) + nbrs[k]) * CH + t];
    outv = fmaf(w2, v, outv);
  }
  outp[((size_t)(b * CH) + t) * NPTS + n] = outv;
}

extern "C" void kernel_launch(void* const* d_in, const int* in_sizes, int n_in,
                              void* d_out, int out_size, void* d_ws, size_t ws_size,
                              hipStream_t stream) {
  const float* pc1 = (const float*)d_in[0];
  const float* pc2 = (const float*)d_in[1];
  const float* f1 = (const float*)d_in[2];
  const float* f2 = (const float*)d_in[3];
  const float* W0 = (const float*)d_in[4];
  const float* b0 = (const float*)d_in[5];
  const float* W1 = (const float*)d_in[6];
  const float* b1 = (const float*)d_in[7];
  const float* W2 = (const float*)d_in[8];
  const float* b2 = (const float*)d_in[9];
  const float* wn1_W1 = (const float*)d_in[10];
  const float* wn1_b1 = (const float*)d_in[11];
  const float* wn1_g = (const float*)d_in[12];
  const float* wn1_be = (const float*)d_in[13];
  const float* wn1_m = (const float*)d_in[14];
  const float* wn1_v = (const float*)d_in[15];
  const float* wn1_W2 = (const float*)d_in[16];
  const float* wn1_b2 = (const float*)d_in[17];
  const float* wn2_W1 = (const float*)d_in[18];
  const float* wn2_b1 = (const float*)d_in[19];
  const float* wn2_g = (const float*)d_in[20];
  const float* wn2_be = (const float*)d_in[21];
  const float* wn2_m = (const float*)d_in[22];
  const float* wn2_v = (const float*)d_in[23];
  const float* wn2_W2 = (const float*)d_in[24];
  const float* wn2_b2 = (const float*)d_in[25];

  float* ws = (float*)d_ws;
  const size_t FEAT = (size_t)NB * NPTS * CH;  // 2097152
  float* f1t = ws;
  float* f2t = f1t + FEAT;
  float* out1 = f2t + FEAT;
  float* W0T = out1 + FEAT;
  float* W1T = W0T + (size_t)INC * CH;
  float* W2T = W1T + (size_t)CH * CH;
  int* idx1 = (int*)(W2T + (size_t)CH * CH);
  int* idx2 = idx1 + (size_t)NB * NPTS * KNB;

  transpose_feat<<<NB * NPTS, 256, 0, stream>>>(f1, f1t);
  transpose_feat<<<NB * NPTS, 256, 0, stream>>>(f2, f2t);
  transpose_w<<<(INC * CH + 255) / 256, 256, 0, stream>>>(W0, W0T, CH, INC);
  transpose_w<<<(CH * CH + 255) / 256, 256, 0, stream>>>(W1, W1T, CH, CH);
  transpose_w<<<(CH * CH + 255) / 256, 256, 0, stream>>>(W2, W2T, CH, CH);
  knn_kernel<<<NB * NPTS / 4, 256, 0, stream>>>(pc1, pc2, idx1);
  knn_kernel<<<NB * NPTS / 4, 256, 0, stream>>>(pc1, pc1, idx2);
  stage1_kernel<<<NB * NPTS, 256, 0, stream>>>(
      f1t, f2t, pc1, pc2, idx1, W0T, b0, W1T, b1, W2T, b2,
      wn1_W1, wn1_b1, wn1_g, wn1_be, wn1_m, wn1_v, wn1_W2, wn1_b2, out1);
  stage2_kernel<<<NB * NPTS, 256, 0, stream>>>(
      out1, pc1, idx2, wn2_W1, wn2_b1, wn2_g, wn2_be, wn2_m, wn2_v, wn2_W2, wn2_b2,
      (float*)d_out);
}

// Round 3
// 390.265 us; speedup vs baseline: 3.2437x; 3.2437x over previous
//
#include <hip/hip_runtime.h>
#include <math.h>

#define KNB 16
#define NPTS 4096
#define NB 2
#define CH 256
#define BNEPS 1e-5f

#define MTOT (NB * NPTS * KNB)   // 131072 rows of (b,n,k)
#define KPAD0 544                // 515 padded to 17*32
#define BM 128                   // GEMM M tile
#define BKC 32                   // GEMM K chunk

typedef short bf16x8 __attribute__((ext_vector_type(8)));
typedef float f32x4 __attribute__((ext_vector_type(4)));

__device__ __forceinline__ unsigned short f2bf(float x) {
  unsigned u = __float_as_uint(x);
  return (unsigned short)((u + 0x7fffu + ((u >> 16) & 1u)) >> 16);
}
__device__ __forceinline__ float bf2f(unsigned short h) {
  return __uint_as_float(((unsigned)h) << 16);
}

#define GLOAD_LDS16(g, l)                                                     \
  __builtin_amdgcn_global_load_lds(                                           \
      (const __attribute__((address_space(1))) unsigned int*)(g),             \
      (__attribute__((address_space(3))) unsigned int*)(l), 16, 0, 0)

// ---------------- KNN: one wave per query, top-16 ----------------
__global__ __launch_bounds__(256) void knn_kernel(const float* __restrict__ q,
                                                  const float* __restrict__ p,
                                                  int* __restrict__ idx_out) {
  int gw = (blockIdx.x * 256 + threadIdx.x) >> 6;
  int lane = threadIdx.x & 63;
  if (gw >= NB * NPTS) return;
  int b = gw >> 12, n = gw & 4095;
  const float* qb = q + (size_t)b * 3 * NPTS;
  const float* pb = p + (size_t)b * 3 * NPTS;
  float qx = qb[n], qy = qb[NPTS + n], qz = qb[2 * NPTS + n];
  float qn = __fadd_rn(__fadd_rn(__fmul_rn(qx, qx), __fmul_rn(qy, qy)), __fmul_rn(qz, qz));
  float ld[KNB];
  int li[KNB];
#pragma unroll
  for (int s = 0; s < KNB; ++s) { ld[s] = INFINITY; li[s] = 0x7fffffff; }
  for (int j = lane; j < NPTS; j += 64) {
    float px = pb[j], py = pb[NPTS + j], pz = pb[2 * NPTS + j];
    float dot = __fadd_rn(__fadd_rn(__fmul_rn(qx, px), __fmul_rn(qy, py)), __fmul_rn(qz, pz));
    float pn = __fadd_rn(__fadd_rn(__fmul_rn(px, px), __fmul_rn(py, py)), __fmul_rn(pz, pz));
    float d = __fadd_rn(__fsub_rn(qn, __fmul_rn(2.f, dot)), pn);
    if (d < ld[KNB - 1]) {
      ld[KNB - 1] = d;
      li[KNB - 1] = j;
#pragma unroll
      for (int s = KNB - 1; s > 0; --s) {
        bool sw = ld[s] < ld[s - 1];
        if (sw) {
          float td = ld[s]; ld[s] = ld[s - 1]; ld[s - 1] = td;
          int ti = li[s]; li[s] = li[s - 1]; li[s - 1] = ti;
        }
      }
    }
  }
  int* op = idx_out + (size_t)gw * KNB;
  for (int r = 0; r < KNB; ++r) {
    float bd = ld[0];
    int bi = li[0];
#pragma unroll
    for (int off = 1; off < 64; off <<= 1) {
      float od = __shfl_xor(bd, off);
      int oi = __shfl_xor(bi, off);
      if (od < bd || (od == bd && oi < bi)) { bd = od; bi = oi; }
    }
    if (lane == 0) op[r] = bi;
    if (li[0] == bi) {
#pragma unroll
      for (int s = 0; s < KNB - 1; ++s) { ld[s] = ld[s + 1]; li[s] = li[s + 1]; }
      ld[KNB - 1] = INFINITY;
      li[KNB - 1] = 0x7fffffff;
    }
  }
}

// ---------------- transpose+convert feature [B,C,N] f32 -> [B*N][C] bf16 ----------------
__global__ __launch_bounds__(256) void conv_feat(const float* __restrict__ in,
                                                 unsigned short* __restrict__ out) {
  int bn = blockIdx.x;
  int b = bn >> 12, n = bn & 4095;
  int c = threadIdx.x;
  out[(size_t)bn * CH + c] = f2bf(in[((size_t)(b * CH + c)) * NPTS + n]);
}

// ---------------- convert weights to bf16 (keep [out][in] layout, pad W0 K to 544) --------
__global__ __launch_bounds__(544) void conv_w(const float* __restrict__ W0,
                                              const float* __restrict__ W1,
                                              const float* __restrict__ W2,
                                              unsigned short* __restrict__ W0b,
                                              unsigned short* __restrict__ W1b,
                                              unsigned short* __restrict__ W2b) {
  int r = blockIdx.x, c = threadIdx.x;
  if (r < 256) {
    W0b[r * KPAD0 + c] = (c < 515) ? f2bf(W0[r * 515 + c]) : (unsigned short)0;
  } else if (r < 512) {
    int rr = r - 256;
    if (c < 256) W1b[rr * 256 + c] = f2bf(W1[rr * 256 + c]);
  } else {
    int rr = r - 512;
    if (c < 256) W2b[rr * 256 + c] = f2bf(W2[rr * 256 + c]);
  }
}

// ---------------- per-row direction (bf16, padded to 32) + weightnet1 hidden (f32) --------
__global__ __launch_bounds__(256) void dir_kernel(
    const float* __restrict__ pc1, const float* __restrict__ pc2,
    const int* __restrict__ idx1,
    const float* __restrict__ wW1, const float* __restrict__ wb1,
    const float* __restrict__ wg, const float* __restrict__ wbe,
    const float* __restrict__ wmn, const float* __restrict__ wv,
    unsigned short* __restrict__ dirb, float* __restrict__ h1wn) {
  int m = blockIdx.x * 256 + threadIdx.x;  // 0..131071
  int bn = m >> 4;
  int b = bn >> 12, n = bn & 4095;
  int j = idx1[m];
  const float* p1 = pc1 + (size_t)b * 3 * NPTS;
  const float* p2 = pc2 + (size_t)b * 3 * NPTS;
  float d0 = p2[j] - p1[n];
  float d1 = p2[NPTS + j] - p1[NPTS + n];
  float d2 = p2[2 * NPTS + j] - p1[2 * NPTS + n];
  unsigned short row[32];
#pragma unroll
  for (int c = 0; c < 32; ++c) row[c] = 0;
  row[0] = f2bf(d0); row[1] = f2bf(d1); row[2] = f2bf(d2);
  float4* dp = (float4*)(dirb + (size_t)m * 32);
  const float4* sp = (const float4*)row;
  dp[0] = sp[0]; dp[1] = sp[1]; dp[2] = sp[2]; dp[3] = sp[3];
  float dv[3] = {d0, d1, d2};
#pragma unroll
  for (int jj = 0; jj < 8; ++jj) {
    float hv = wb1[jj];
#pragma unroll
    for (int c = 0; c < 3; ++c) hv = fmaf(dv[c], wW1[jj * 3 + c], hv);
    hv = wg[jj] * (hv - wmn[jj]) * (1.f / sqrtf(wv[jj] + BNEPS)) + wbe[jj];
    h1wn[(size_t)m * 8 + jj] = fmaxf(hv, 0.f);
  }
}

// ---------------- MFMA GEMM: [MTOT x K] @ [K x 256] -> leaky -> bf16 dst ----------------
// MODE 0: A gathered (f1 | f2[nbr] | dir), K = 544.  MODE 1: A = Asrc (bf16 h), K = 256.
// Tile: BM=128 x BN=256(all), BK=32, 512 threads = 8 waves (2m x 4n), wave = 64x64.
template <int MODE>
__global__ __launch_bounds__(512) void gemm_kernel(
    const unsigned short* __restrict__ f1b, const unsigned short* __restrict__ f2b,
    const unsigned short* __restrict__ dirb, const int* __restrict__ idx1,
    const unsigned short* __restrict__ Asrc, const unsigned short* __restrict__ Wb,
    const float* __restrict__ bias, unsigned short* __restrict__ dst,
    int nchunks, int kpad) {
  __shared__ char smem[8192 + 16384];  // As [128][32] bf16, Bs [256][32] bf16 (quad-swizzled)
  const int tid = threadIdx.x;
  const int lane = tid & 63;
  const int w = tid >> 6;
  const int wm = w >> 2, wn = w & 3;
  const int m0 = blockIdx.x * BM;

  f32x4 acc[4][4];
#pragma unroll
  for (int nf = 0; nf < 4; ++nf) {
    float bv = bias[wn * 64 + nf * 16 + (lane & 15)];
#pragma unroll
    for (int mf = 0; mf < 4; ++mf) acc[mf][nf] = (f32x4){bv, bv, bv, bv};
  }

  // staging slot geometry (linear LDS dest; source pre-swizzled, rule #21)
  const int ar = tid >> 2;                       // A row 0..127
  const int aql = (tid & 3) ^ ((ar >> 1) & 3);   // logical quad for this slot
  const int am = m0 + ar;
  // neighbor row in f2b needs the batch offset: b = am >> 16, row = b*4096 + idx
  const int anbr = (MODE == 0) ? (((am >> 16) << 12) + idx1[am]) : 0;
  const int br0 = tid >> 2;                      // B rows 0..127
  const int bq0 = (tid & 3) ^ ((br0 >> 1) & 3);
  const int br1 = (tid + 512) >> 2;              // B rows 128..255
  const int bq1 = (tid & 3) ^ ((br1 >> 1) & 3);

  char* AsW = smem + (w << 10);                  // wave-uniform LDS bases
  char* BsW0 = smem + 8192 + (w << 10);
  char* BsW1 = smem + 8192 + 8192 + (w << 10);

  for (int kc = 0; kc < nchunks; ++kc) {
    __syncthreads();  // previous chunk's compute done before overwrite
    const unsigned short* ga;
    if (MODE == 0) {
      if (kc < 8)
        ga = f1b + ((am >> 4) << 8) + kc * 32 + aql * 8;
      else if (kc < 16)
        ga = f2b + ((size_t)anbr << 8) + (kc - 8) * 32 + aql * 8;
      else
        ga = dirb + ((size_t)am << 5) + aql * 8;
    } else {
      ga = Asrc + ((size_t)am << 8) + kc * 32 + aql * 8;
    }
    GLOAD_LDS16(ga, AsW);
    GLOAD_LDS16(Wb + (size_t)br0 * kpad + kc * 32 + bq0 * 8, BsW0);
    GLOAD_LDS16(Wb + (size_t)br1 * kpad + kc * 32 + bq1 * 8, BsW1);
    __syncthreads();  // compiler drains vmcnt before barrier

    bf16x8 af[4], bfr[4];
#pragma unroll
    for (int mf = 0; mf < 4; ++mf) {
      int r = wm * 64 + mf * 16 + (lane & 15);
      int off = r * 64 + ((((lane >> 4)) ^ ((r >> 1) & 3)) << 4);
      af[mf] = *(const bf16x8*)(smem + off);
    }
#pragma unroll
    for (int nf = 0; nf < 4; ++nf) {
      int r = wn * 64 + nf * 16 + (lane & 15);
      int off = r * 64 + ((((lane >> 4)) ^ ((r >> 1) & 3)) << 4);
      bfr[nf] = *(const bf16x8*)(smem + 8192 + off);
    }
#pragma unroll
    for (int mf = 0; mf < 4; ++mf)
#pragma unroll
      for (int nf = 0; nf < 4; ++nf)
        acc[mf][nf] = __builtin_amdgcn_mfma_f32_16x16x32_bf16(af[mf], bfr[nf], acc[mf][nf], 0, 0, 0);
  }

  // epilogue: leaky -> bf16 store
#pragma unroll
  for (int mf = 0; mf < 4; ++mf) {
#pragma unroll
    for (int nf = 0; nf < 4; ++nf) {
      int n = wn * 64 + nf * 16 + (lane & 15);
#pragma unroll
      for (int j = 0; j < 4; ++j) {
        int m = m0 + wm * 64 + mf * 16 + (lane >> 4) * 4 + j;
        float v = acc[mf][nf][j];
        v = v >= 0.f ? v : 0.1f * v;
        dst[(size_t)m * 256 + n] = f2bf(v);
      }
    }
  }
}

// ---------------- apply weightnet1, reduce over K -> out1 [8192][256] f32 ----------------
__global__ __launch_bounds__(256) void wreduce_kernel(
    const unsigned short* __restrict__ h2, const float* __restrict__ h1wn,
    const float* __restrict__ wW2, const float* __restrict__ wb2,
    float* __restrict__ out1) {
  __shared__ float g[KNB][8];
  int bn = blockIdx.x;
  int t = threadIdx.x;
  if (t < 128) g[t >> 3][t & 7] = h1wn[(size_t)(bn * KNB + (t >> 3)) * 8 + (t & 7)];
  float wrow[8];
#pragma unroll
  for (int jj = 0; jj < 8; ++jj) wrow[jj] = wW2[t * 8 + jj];
  float wb = wb2[t];
  __syncthreads();
  float o = 0.f;
#pragma unroll
  for (int k = 0; k < KNB; ++k) {
    float w1 = wb;
#pragma unroll
    for (int jj = 0; jj < 8; ++jj) w1 = fmaf(g[k][jj], wrow[jj], w1);
    float v = bf2f(h2[(size_t)(bn * KNB + k) * 256 + t]);
    o = fmaf(w1, v, o);
  }
  out1[(size_t)bn * 256 + t] = o;
}

// ---------------- stage 2: gather out1, weightnet2, K-reduce, write [B,C,N] ----------------
__global__ __launch_bounds__(256) void stage2_kernel(
    const float* __restrict__ out1, const float* __restrict__ pc1,
    const int* __restrict__ idx2,
    const float* __restrict__ wn_W1, const float* __restrict__ wn_b1,
    const float* __restrict__ wn_g, const float* __restrict__ wn_be,
    const float* __restrict__ wn_m, const float* __restrict__ wn_v,
    const float* __restrict__ wn_W2, const float* __restrict__ wn_b2,
    float* __restrict__ outp) {
  __shared__ float h1[KNB][8];
  __shared__ int nbrs[KNB];
  int bn = blockIdx.x;
  int b = bn >> 12, n = bn & 4095;
  int t = threadIdx.x;
  if (t < KNB) nbrs[t] = idx2[(size_t)bn * KNB + t];
  __syncthreads();
  if (t < 128) {
    int k = t >> 3, jj = t & 7;
    int j = nbrs[k];
    const float* p1 = pc1 + (size_t)b * 3 * NPTS;
    float d0 = p1[j] - p1[n];
    float d1 = p1[NPTS + j] - p1[NPTS + n];
    float d2v = p1[2 * NPTS + j] - p1[2 * NPTS + n];
    float hv = d0 * wn_W1[jj * 3] + d1 * wn_W1[jj * 3 + 1] + d2v * wn_W1[jj * 3 + 2] + wn_b1[jj];
    hv = wn_g[jj] * (hv - wn_m[jj]) * (1.f / sqrtf(wn_v[jj] + BNEPS)) + wn_be[jj];
    h1[k][jj] = fmaxf(hv, 0.f);
  }
  __syncthreads();
  float wrow[8];
#pragma unroll
  for (int jj = 0; jj < 8; ++jj) wrow[jj] = wn_W2[t * 8 + jj];
  float wb = wn_b2[t];
  float outv = 0.f;
#pragma unroll
  for (int k = 0; k < KNB; ++k) {
    float w2 = wb;
#pragma unroll
    for (int jj = 0; jj < 8; ++jj) w2 = fmaf(h1[k][jj], wrow[jj], w2);
    float v = out1[((size_t)(b * NPTS) + nbrs[k]) * CH + t];
    outv = fmaf(w2, v, outv);
  }
  outp[((size_t)(b * CH) + t) * NPTS + n] = outv;
}

extern "C" void kernel_launch(void* const* d_in, const int* in_sizes, int n_in,
                              void* d_out, int out_size, void* d_ws, size_t ws_size,
                              hipStream_t stream) {
  const float* pc1 = (const float*)d_in[0];
  const float* pc2 = (const float*)d_in[1];
  const float* f1 = (const float*)d_in[2];
  const float* f2 = (const float*)d_in[3];
  const float* W0 = (const float*)d_in[4];
  const float* b0 = (const float*)d_in[5];
  const float* W1 = (const float*)d_in[6];
  const float* b1 = (const float*)d_in[7];
  const float* W2 = (const float*)d_in[8];
  const float* b2 = (const float*)d_in[9];
  const float* wn1_W1 = (const float*)d_in[10];
  const float* wn1_b1 = (const float*)d_in[11];
  const float* wn1_g = (const float*)d_in[12];
  const float* wn1_be = (const float*)d_in[13];
  const float* wn1_m = (const float*)d_in[14];
  const float* wn1_v = (const float*)d_in[15];
  const float* wn1_W2 = (const float*)d_in[16];
  const float* wn1_b2 = (const float*)d_in[17];
  const float* wn2_W1 = (const float*)d_in[18];
  const float* wn2_b1 = (const float*)d_in[19];
  const float* wn2_g = (const float*)d_in[20];
  const float* wn2_be = (const float*)d_in[21];
  const float* wn2_m = (const float*)d_in[22];
  const float* wn2_v = (const float*)d_in[23];
  const float* wn2_W2 = (const float*)d_in[24];
  const float* wn2_b2 = (const float*)d_in[25];

  unsigned short* f1b = (unsigned short*)d_ws;
  unsigned short* f2b = f1b + (size_t)NB * NPTS * CH;
  unsigned short* W0b = f2b + (size_t)NB * NPTS * CH;
  unsigned short* W1b = W0b + (size_t)256 * KPAD0;
  unsigned short* W2b = W1b + (size_t)256 * 256;
  unsigned short* dirb = W2b + (size_t)256 * 256;
  unsigned short* h = dirb + (size_t)MTOT * 32;
  float* h1wn = (float*)(h + (size_t)MTOT * 256);
  float* out1 = h1wn + (size_t)MTOT * 8;
  int* idx1 = (int*)(out1 + (size_t)NB * NPTS * CH);
  int* idx2 = idx1 + (size_t)MTOT;

  knn_kernel<<<NB * NPTS / 4, 256, 0, stream>>>(pc1, pc2, idx1);
  knn_kernel<<<NB * NPTS / 4, 256, 0, stream>>>(pc1, pc1, idx2);
  conv_feat<<<NB * NPTS, 256, 0, stream>>>(f1, f1b);
  conv_feat<<<NB * NPTS, 256, 0, stream>>>(f2, f2b);
  conv_w<<<768, 544, 0, stream>>>(W0, W1, W2, W0b, W1b, W2b);
  dir_kernel<<<MTOT / 256, 256, 0, stream>>>(pc1, pc2, idx1, wn1_W1, wn1_b1, wn1_g,
                                             wn1_be, wn1_m, wn1_v, dirb, h1wn);
  gemm_kernel<0><<<MTOT / BM, 512, 0, stream>>>(
      f1b, f2b, dirb, idx1, (const unsigned short*)nullptr, W0b, b0, h, 17, KPAD0);
  gemm_kernel<1><<<MTOT / BM, 512, 0, stream>>>(
      f1b, f2b, dirb, idx1, h, W1b, b1, h, 8, 256);
  gemm_kernel<1><<<MTOT / BM, 512, 0, stream>>>(
      f1b, f2b, dirb, idx1, h, W2b, b2, h, 8, 256);
  wreduce_kernel<<<NB * NPTS, 256, 0, stream>>>(h, h1wn, wn1_W2, wn1_b2, out1);
  stage2_kernel<<<NB * NPTS, 256, 0, stream>>>(
      out1, pc1, idx2, wn2_W1, wn2_b1, wn2_g, wn2_be, wn2_m, wn2_v, wn2_W2, wn2_b2,
      (float*)d_out);
}

// Round 4
// 367.101 us; speedup vs baseline: 3.4484x; 1.0631x over previous
//
#include <hip/hip_runtime.h>
#include <math.h>

#define KNB 16
#define NPTS 4096
#define NB 2
#define CH 256
#define BNEPS 1e-5f

#define MTOT (NB * NPTS * KNB)   // 131072 rows of (b,n,k)
#define KPAD0 544                // 515 padded to 17*32
#define BM 128                   // GEMM M tile

typedef short bf16x8 __attribute__((ext_vector_type(8)));
typedef float f32x4 __attribute__((ext_vector_type(4)));

__device__ __forceinline__ unsigned short f2bf(float x) {
  unsigned u = __float_as_uint(x);
  return (unsigned short)((u + 0x7fffu + ((u >> 16) & 1u)) >> 16);
}
__device__ __forceinline__ float bf2f(unsigned short h) {
  return __uint_as_float(((unsigned)h) << 16);
}

#define GLOAD_LDS16(g, l)                                                     \
  __builtin_amdgcn_global_load_lds(                                           \
      (const __attribute__((address_space(1))) unsigned int*)(g),             \
      (__attribute__((address_space(3))) unsigned int*)(l), 16, 0, 0)

// ---------------- pack points: [B,3,N] f32 -> [B*N] float4 (x,y,z,|p|^2) ----------------
// norm uses the exact same __fmul_rn/__fadd_rn ordering as the validated knn arithmetic.
__global__ __launch_bounds__(256) void pack_pts(const float* __restrict__ in,
                                                float4* __restrict__ out) {
  int id = blockIdx.x * 256 + threadIdx.x;  // 0..8191
  int b = id >> 12, n = id & 4095;
  const float* pb = in + (size_t)b * 3 * NPTS;
  float x = pb[n], y = pb[NPTS + n], z = pb[2 * NPTS + n];
  float nn = __fadd_rn(__fadd_rn(__fmul_rn(x, x), __fmul_rn(y, y)), __fmul_rn(z, z));
  out[id] = make_float4(x, y, z, nn);
}

// ---------------- fused KNN (both searches), one wave per query, top-16 ----------------
// wave-uniform rejection threshold: thr = min over lanes of per-lane 16th; any lane's 16th
// is >= global-16th-so-far, so rejecting d > thr is safe (d == thr kept for tie stability).
__global__ __launch_bounds__(256) void knn2_kernel(const float4* __restrict__ pk1,
                                                   const float4* __restrict__ pk2,
                                                   int* __restrict__ idx1,
                                                   int* __restrict__ idx2) {
  int gw = (blockIdx.x * 256 + threadIdx.x) >> 6;  // 0..16383
  int lane = threadIdx.x & 63;
  int which = gw >> 13;     // 0: pc1 queries vs pc2 -> idx1 ; 1: pc1 vs pc1 -> idx2
  int qi = gw & 8191;       // b*4096 + n
  int b = qi >> 12;
  const float4* pts = (which ? pk1 : pk2) + ((size_t)b << 12);
  float4 qp = pk1[qi];
  float qx = qp.x, qy = qp.y, qz = qp.z, qn = qp.w;

  float ld[KNB];
  int li[KNB];
#pragma unroll
  for (int s = 0; s < KNB; ++s) { ld[s] = INFINITY; li[s] = 0x7fffffff; }

  float thr = INFINITY;
  for (int chunk = 0; chunk < 4; ++chunk) {
    int base = (chunk << 10) + lane;
#pragma unroll
    for (int it = 0; it < 16; ++it) {
      int j = base + (it << 6);
      float4 pt = pts[j];
      float dot = __fadd_rn(__fadd_rn(__fmul_rn(qx, pt.x), __fmul_rn(qy, pt.y)),
                            __fmul_rn(qz, pt.z));
      float d = __fadd_rn(__fsub_rn(qn, __fmul_rn(2.f, dot)), pt.w);
      if (d <= thr && d < ld[KNB - 1]) {
        ld[KNB - 1] = d;
        li[KNB - 1] = j;
#pragma unroll
        for (int s = KNB - 1; s > 0; --s) {
          bool sw = ld[s] < ld[s - 1];
          if (sw) {
            float td = ld[s]; ld[s] = ld[s - 1]; ld[s - 1] = td;
            int ti = li[s]; li[s] = li[s - 1]; li[s - 1] = ti;
          }
        }
      }
    }
    float m = ld[KNB - 1];
#pragma unroll
    for (int off = 1; off < 64; off <<= 1) m = fminf(m, __shfl_xor(m, off));
    thr = m;
  }

  // 16-round cross-lane lexicographic-min merge (matches top_k stability)
  int* op = (which ? idx2 : idx1) + (size_t)qi * KNB;
  for (int r = 0; r < KNB; ++r) {
    float bd = ld[0];
    int bi = li[0];
#pragma unroll
    for (int off = 1; off < 64; off <<= 1) {
      float od = __shfl_xor(bd, off);
      int oi = __shfl_xor(bi, off);
      if (od < bd || (od == bd && oi < bi)) { bd = od; bi = oi; }
    }
    if (lane == 0) op[r] = bi;
    if (li[0] == bi) {
#pragma unroll
      for (int s = 0; s < KNB - 1; ++s) { ld[s] = ld[s + 1]; li[s] = li[s + 1]; }
      ld[KNB - 1] = INFINITY;
      li[KNB - 1] = 0x7fffffff;
    }
  }
}

// ---------------- transpose+convert feature [B,C,N] f32 -> [B*N][C] bf16 ----------------
__global__ __launch_bounds__(256) void conv_feat(const float* __restrict__ in,
                                                 unsigned short* __restrict__ out) {
  int bn = blockIdx.x;
  int b = bn >> 12, n = bn & 4095;
  int c = threadIdx.x;
  out[(size_t)bn * CH + c] = f2bf(in[((size_t)(b * CH + c)) * NPTS + n]);
}

// ---------------- convert weights to bf16 (keep [out][in] layout, pad W0 K to 544) --------
__global__ __launch_bounds__(544) void conv_w(const float* __restrict__ W0,
                                              const float* __restrict__ W1,
                                              const float* __restrict__ W2,
                                              unsigned short* __restrict__ W0b,
                                              unsigned short* __restrict__ W1b,
                                              unsigned short* __restrict__ W2b) {
  int r = blockIdx.x, c = threadIdx.x;
  if (r < 256) {
    W0b[r * KPAD0 + c] = (c < 515) ? f2bf(W0[r * 515 + c]) : (unsigned short)0;
  } else if (r < 512) {
    int rr = r - 256;
    if (c < 256) W1b[rr * 256 + c] = f2bf(W1[rr * 256 + c]);
  } else {
    int rr = r - 512;
    if (c < 256) W2b[rr * 256 + c] = f2bf(W2[rr * 256 + c]);
  }
}

// ---------------- per-row direction (bf16, padded to 32) + weightnet1 hidden (f32) --------
__global__ __launch_bounds__(256) void dir_kernel(
    const float* __restrict__ pc1, const float* __restrict__ pc2,
    const int* __restrict__ idx1,
    const float* __restrict__ wW1, const float* __restrict__ wb1,
    const float* __restrict__ wg, const float* __restrict__ wbe,
    const float* __restrict__ wmn, const float* __restrict__ wv,
    unsigned short* __restrict__ dirb, float* __restrict__ h1wn) {
  int m = blockIdx.x * 256 + threadIdx.x;  // 0..131071
  int bn = m >> 4;
  int b = bn >> 12, n = bn & 4095;
  int j = idx1[m];
  const float* p1 = pc1 + (size_t)b * 3 * NPTS;
  const float* p2 = pc2 + (size_t)b * 3 * NPTS;
  float d0 = p2[j] - p1[n];
  float d1 = p2[NPTS + j] - p1[NPTS + n];
  float d2 = p2[2 * NPTS + j] - p1[2 * NPTS + n];
  unsigned short row[32];
#pragma unroll
  for (int c = 0; c < 32; ++c) row[c] = 0;
  row[0] = f2bf(d0); row[1] = f2bf(d1); row[2] = f2bf(d2);
  float4* dp = (float4*)(dirb + (size_t)m * 32);
  const float4* sp = (const float4*)row;
  dp[0] = sp[0]; dp[1] = sp[1]; dp[2] = sp[2]; dp[3] = sp[3];
  float dv[3] = {d0, d1, d2};
#pragma unroll
  for (int jj = 0; jj < 8; ++jj) {
    float hv = wb1[jj];
#pragma unroll
    for (int c = 0; c < 3; ++c) hv = fmaf(dv[c], wW1[jj * 3 + c], hv);
    hv = wg[jj] * (hv - wmn[jj]) * (1.f / sqrtf(wv[jj] + BNEPS)) + wbe[jj];
    h1wn[(size_t)m * 8 + jj] = fmaxf(hv, 0.f);
  }
}

// ---------------- MFMA GEMM: [MTOT x K] @ [K x 256] -> leaky -> bf16 dst ----------------
template <int MODE>
__global__ __launch_bounds__(512) void gemm_kernel(
    const unsigned short* __restrict__ f1b, const unsigned short* __restrict__ f2b,
    const unsigned short* __restrict__ dirb, const int* __restrict__ idx1,
    const unsigned short* __restrict__ Asrc, const unsigned short* __restrict__ Wb,
    const float* __restrict__ bias, unsigned short* __restrict__ dst,
    int nchunks, int kpad) {
  __shared__ char smem[8192 + 16384];  // As [128][32] bf16, Bs [256][32] bf16 (quad-swizzled)
  const int tid = threadIdx.x;
  const int lane = tid & 63;
  const int w = tid >> 6;
  const int wm = w >> 2, wn = w & 3;
  const int m0 = blockIdx.x * BM;

  f32x4 acc[4][4];
#pragma unroll
  for (int nf = 0; nf < 4; ++nf) {
    float bv = bias[wn * 64 + nf * 16 + (lane & 15)];
#pragma unroll
    for (int mf = 0; mf < 4; ++mf) acc[mf][nf] = (f32x4){bv, bv, bv, bv};
  }

  const int ar = tid >> 2;                       // A row 0..127
  const int aql = (tid & 3) ^ ((ar >> 1) & 3);   // logical quad for this slot
  const int am = m0 + ar;
  const int anbr = (MODE == 0) ? (((am >> 16) << 12) + idx1[am]) : 0;
  const int br0 = tid >> 2;
  const int bq0 = (tid & 3) ^ ((br0 >> 1) & 3);
  const int br1 = (tid + 512) >> 2;
  const int bq1 = (tid & 3) ^ ((br1 >> 1) & 3);

  char* AsW = smem + (w << 10);
  char* BsW0 = smem + 8192 + (w << 10);
  char* BsW1 = smem + 8192 + 8192 + (w << 10);

  for (int kc = 0; kc < nchunks; ++kc) {
    __syncthreads();
    const unsigned short* ga;
    if (MODE == 0) {
      if (kc < 8)
        ga = f1b + ((am >> 4) << 8) + kc * 32 + aql * 8;
      else if (kc < 16)
        ga = f2b + ((size_t)anbr << 8) + (kc - 8) * 32 + aql * 8;
      else
        ga = dirb + ((size_t)am << 5) + aql * 8;
    } else {
      ga = Asrc + ((size_t)am << 8) + kc * 32 + aql * 8;
    }
    GLOAD_LDS16(ga, AsW);
    GLOAD_LDS16(Wb + (size_t)br0 * kpad + kc * 32 + bq0 * 8, BsW0);
    GLOAD_LDS16(Wb + (size_t)br1 * kpad + kc * 32 + bq1 * 8, BsW1);
    __syncthreads();

    bf16x8 af[4], bfr[4];
#pragma unroll
    for (int mf = 0; mf < 4; ++mf) {
      int r = wm * 64 + mf * 16 + (lane & 15);
      int off = r * 64 + ((((lane >> 4)) ^ ((r >> 1) & 3)) << 4);
      af[mf] = *(const bf16x8*)(smem + off);
    }
#pragma unroll
    for (int nf = 0; nf < 4; ++nf) {
      int r = wn * 64 + nf * 16 + (lane & 15);
      int off = r * 64 + ((((lane >> 4)) ^ ((r >> 1) & 3)) << 4);
      bfr[nf] = *(const bf16x8*)(smem + 8192 + off);
    }
#pragma unroll
    for (int mf = 0; mf < 4; ++mf)
#pragma unroll
      for (int nf = 0; nf < 4; ++nf)
        acc[mf][nf] = __builtin_amdgcn_mfma_f32_16x16x32_bf16(af[mf], bfr[nf], acc[mf][nf], 0, 0, 0);
  }

#pragma unroll
  for (int mf = 0; mf < 4; ++mf) {
#pragma unroll
    for (int nf = 0; nf < 4; ++nf) {
      int n = wn * 64 + nf * 16 + (lane & 15);
#pragma unroll
      for (int j = 0; j < 4; ++j) {
        int m = m0 + wm * 64 + mf * 16 + (lane >> 4) * 4 + j;
        float v = acc[mf][nf][j];
        v = v >= 0.f ? v : 0.1f * v;
        dst[(size_t)m * 256 + n] = f2bf(v);
      }
    }
  }
}

// ---------------- apply weightnet1, reduce over K -> out1 [8192][256] f32 ----------------
__global__ __launch_bounds__(256) void wreduce_kernel(
    const unsigned short* __restrict__ h2, const float* __restrict__ h1wn,
    const float* __restrict__ wW2, const float* __restrict__ wb2,
    float* __restrict__ out1) {
  __shared__ float g[KNB][8];
  int bn = blockIdx.x;
  int t = threadIdx.x;
  if (t < 128) g[t >> 3][t & 7] = h1wn[(size_t)(bn * KNB + (t >> 3)) * 8 + (t & 7)];
  float wrow[8];
#pragma unroll
  for (int jj = 0; jj < 8; ++jj) wrow[jj] = wW2[t * 8 + jj];
  float wb = wb2[t];
  __syncthreads();
  float o = 0.f;
#pragma unroll
  for (int k = 0; k < KNB; ++k) {
    float w1 = wb;
#pragma unroll
    for (int jj = 0; jj < 8; ++jj) w1 = fmaf(g[k][jj], wrow[jj], w1);
    float v = bf2f(h2[(size_t)(bn * KNB + k) * 256 + t]);
    o = fmaf(w1, v, o);
  }
  out1[(size_t)bn * 256 + t] = o;
}

// ---------------- stage 2: gather out1, weightnet2, K-reduce, write [B,C,N] ----------------
__global__ __launch_bounds__(256) void stage2_kernel(
    const float* __restrict__ out1, const float* __restrict__ pc1,
    const int* __restrict__ idx2,
    const float* __restrict__ wn_W1, const float* __restrict__ wn_b1,
    const float* __restrict__ wn_g, const float* __restrict__ wn_be,
    const float* __restrict__ wn_m, const float* __restrict__ wn_v,
    const float* __restrict__ wn_W2, const float* __restrict__ wn_b2,
    float* __restrict__ outp) {
  __shared__ float h1[KNB][8];
  __shared__ int nbrs[KNB];
  int bn = blockIdx.x;
  int b = bn >> 12, n = bn & 4095;
  int t = threadIdx.x;
  if (t < KNB) nbrs[t] = idx2[(size_t)bn * KNB + t];
  __syncthreads();
  if (t < 128) {
    int k = t >> 3, jj = t & 7;
    int j = nbrs[k];
    const float* p1 = pc1 + (size_t)b * 3 * NPTS;
    float d0 = p1[j] - p1[n];
    float d1 = p1[NPTS + j] - p1[NPTS + n];
    float d2v = p1[2 * NPTS + j] - p1[2 * NPTS + n];
    float hv = d0 * wn_W1[jj * 3] + d1 * wn_W1[jj * 3 + 1] + d2v * wn_W1[jj * 3 + 2] + wn_b1[jj];
    hv = wn_g[jj] * (hv - wn_m[jj]) * (1.f / sqrtf(wn_v[jj] + BNEPS)) + wn_be[jj];
    h1[k][jj] = fmaxf(hv, 0.f);
  }
  __syncthreads();
  float wrow[8];
#pragma unroll
  for (int jj = 0; jj < 8; ++jj) wrow[jj] = wn_W2[t * 8 + jj];
  float wb = wn_b2[t];
  float outv = 0.f;
#pragma unroll
  for (int k = 0; k < KNB; ++k) {
    float w2 = wb;
#pragma unroll
    for (int jj = 0; jj < 8; ++jj) w2 = fmaf(h1[k][jj], wrow[jj], w2);
    float v = out1[((size_t)(b * NPTS) + nbrs[k]) * CH + t];
    outv = fmaf(w2, v, outv);
  }
  outp[((size_t)(b * CH) + t) * NPTS + n] = outv;
}

extern "C" void kernel_launch(void* const* d_in, const int* in_sizes, int n_in,
                              void* d_out, int out_size, void* d_ws, size_t ws_size,
                              hipStream_t stream) {
  const float* pc1 = (const float*)d_in[0];
  const float* pc2 = (const float*)d_in[1];
  const float* f1 = (const float*)d_in[2];
  const float* f2 = (const float*)d_in[3];
  const float* W0 = (const float*)d_in[4];
  const float* b0 = (const float*)d_in[5];
  const float* W1 = (const float*)d_in[6];
  const float* b1 = (const float*)d_in[7];
  const float* W2 = (const float*)d_in[8];
  const float* b2 = (const float*)d_in[9];
  const float* wn1_W1 = (const float*)d_in[10];
  const float* wn1_b1 = (const float*)d_in[11];
  const float* wn1_g = (const float*)d_in[12];
  const float* wn1_be = (const float*)d_in[13];
  const float* wn1_m = (const float*)d_in[14];
  const float* wn1_v = (const float*)d_in[15];
  const float* wn1_W2 = (const float*)d_in[16];
  const float* wn1_b2 = (const float*)d_in[17];
  const float* wn2_W1 = (const float*)d_in[18];
  const float* wn2_b1 = (const float*)d_in[19];
  const float* wn2_g = (const float*)d_in[20];
  const float* wn2_be = (const float*)d_in[21];
  const float* wn2_m = (const float*)d_in[22];
  const float* wn2_v = (const float*)d_in[23];
  const float* wn2_W2 = (const float*)d_in[24];
  const float* wn2_b2 = (const float*)d_in[25];

  unsigned short* f1b = (unsigned short*)d_ws;
  unsigned short* f2b = f1b + (size_t)NB * NPTS * CH;
  unsigned short* W0b = f2b + (size_t)NB * NPTS * CH;
  unsigned short* W1b = W0b + (size_t)256 * KPAD0;
  unsigned short* W2b = W1b + (size_t)256 * 256;
  unsigned short* dirb = W2b + (size_t)256 * 256;
  unsigned short* h = dirb + (size_t)MTOT * 32;
  float* h1wn = (float*)(h + (size_t)MTOT * 256);
  float* out1 = h1wn + (size_t)MTOT * 8;
  int* idx1 = (int*)(out1 + (size_t)NB * NPTS * CH);
  int* idx2 = idx1 + (size_t)MTOT;
  float4* pk1 = (float4*)(idx2 + (size_t)MTOT);
  float4* pk2 = pk1 + (size_t)NB * NPTS;

  pack_pts<<<NB * NPTS / 256, 256, 0, stream>>>(pc1, pk1);
  pack_pts<<<NB * NPTS / 256, 256, 0, stream>>>(pc2, pk2);
  knn2_kernel<<<NB * NPTS * 2 / 4, 256, 0, stream>>>(pk1, pk2, idx1, idx2);
  conv_feat<<<NB * NPTS, 256, 0, stream>>>(f1, f1b);
  conv_feat<<<NB * NPTS, 256, 0, stream>>>(f2, f2b);
  conv_w<<<768, 544, 0, stream>>>(W0, W1, W2, W0b, W1b, W2b);
  dir_kernel<<<MTOT / 256, 256, 0, stream>>>(pc1, pc2, idx1, wn1_W1, wn1_b1, wn1_g,
                                             wn1_be, wn1_m, wn1_v, dirb, h1wn);
  gemm_kernel<0><<<MTOT / BM, 512, 0, stream>>>(
      f1b, f2b, dirb, idx1, (const unsigned short*)nullptr, W0b, b0, h, 17, KPAD0);
  gemm_kernel<1><<<MTOT / BM, 512, 0, stream>>>(
      f1b, f2b, dirb, idx1, h, W1b, b1, h, 8, 256);
  gemm_kernel<1><<<MTOT / BM, 512, 0, stream>>>(
      f1b, f2b, dirb, idx1, h, W2b, b2, h, 8, 256);
  wreduce_kernel<<<NB * NPTS, 256, 0, stream>>>(h, h1wn, wn1_W2, wn1_b2, out1);
  stage2_kernel<<<NB * NPTS, 256, 0, stream>>>(
      out1, pc1, idx2, wn2_W1, wn2_b1, wn2_g, wn2_be, wn2_m, wn2_v, wn2_W2, wn2_b2,
      (float*)d_out);
}

// Round 5
// 296.343 us; speedup vs baseline: 4.2717x; 1.2388x over previous
//
#include <hip/hip_runtime.h>
#include <math.h>

#define KNB 16
#define NPTS 4096
#define NB 2
#define CH 256
#define BNEPS 1e-5f

#define MTOT (NB * NPTS * KNB)   // 131072 rows of (b,n,k)
#define KPAD0 544                // 515 padded to 17*32
#define BM 128                   // GEMM M tile

typedef short bf16x8 __attribute__((ext_vector_type(8)));
typedef float f32x4 __attribute__((ext_vector_type(4)));

__device__ __forceinline__ unsigned short f2bf(float x) {
  unsigned u = __float_as_uint(x);
  return (unsigned short)((u + 0x7fffu + ((u >> 16) & 1u)) >> 16);
}
__device__ __forceinline__ float bf2f(unsigned short h) {
  return __uint_as_float(((unsigned)h) << 16);
}

#define GLOAD_LDS16(g, l)                                                     \
  __builtin_amdgcn_global_load_lds(                                           \
      (const __attribute__((address_space(1))) unsigned int*)(g),             \
      (__attribute__((address_space(3))) unsigned int*)(l), 16, 0, 0)

// ---------------- pack points: [B,3,N] f32 -> [B*N] float4 (x,y,z,|p|^2) ----------------
__global__ __launch_bounds__(256) void pack_pts(const float* __restrict__ in,
                                                float4* __restrict__ out) {
  int id = blockIdx.x * 256 + threadIdx.x;  // 0..8191
  int b = id >> 12, n = id & 4095;
  const float* pb = in + (size_t)b * 3 * NPTS;
  float x = pb[n], y = pb[NPTS + n], z = pb[2 * NPTS + n];
  float nn = __fadd_rn(__fadd_rn(__fmul_rn(x, x), __fmul_rn(y, y)), __fmul_rn(z, z));
  out[id] = make_float4(x, y, z, nn);
}

// ---------------- KNN v3: scan/select, one wave per query ----------------
// Pass1: exact f32 distances -> sortable u32 in LDS + per-lane min.
// Threshold: bitonic-64 of lane minima, cutoff idx tuned so 16<=cnt<=128.
// Collect: ballot-rank compaction of u64 keys (sortable_d<<32 | j) -> LDS.
// Select: bitonic-128 sort of keys; lanes 0-15 emit exact lex-(d,j) top-16.
__global__ __launch_bounds__(256) void knn3_kernel(const float4* __restrict__ pk1,
                                                   const float4* __restrict__ pk2,
                                                   int* __restrict__ idx1,
                                                   int* __restrict__ idx2) {
  __shared__ unsigned int sarr[4][4096];
  __shared__ unsigned long long surv[4][128];
  const int wid = threadIdx.x >> 6;
  const int lane = threadIdx.x & 63;
  const int gw = blockIdx.x * 4 + wid;       // 0..16383
  const int which = gw >> 13;                // 0: pc1 vs pc2 -> idx1 ; 1: pc1 vs pc1 -> idx2
  const int qi = gw & 8191;                  // b*4096 + n
  const int b = qi >> 12;
  const float4* pts = (which ? pk1 : pk2) + ((size_t)b << 12);
  float4 qp = pk1[qi];
  const float qx = qp.x, qy = qp.y, qz = qp.z, qn = qp.w;
  unsigned int* S = sarr[wid];

  // ---- pass 1: distances (exact r4 arithmetic) -> sortable u32 ----
  unsigned int mymin = 0xFFFFFFFFu;
#pragma unroll 8
  for (int it = 0; it < 64; ++it) {
    int j = (it << 6) + lane;
    float4 pt = pts[j];
    float dot = __fadd_rn(__fadd_rn(__fmul_rn(qx, pt.x), __fmul_rn(qy, pt.y)),
                          __fmul_rn(qz, pt.z));
    float d = __fadd_rn(__fsub_rn(qn, __fmul_rn(2.f, dot)), pt.w);
    unsigned int u = __float_as_uint(d);
    unsigned int s = u ^ (unsigned int)(((int)u >> 31) | (int)0x80000000);
    S[j] = s;
    mymin = mymin < s ? mymin : s;
  }

  // ---- bitonic sort of 64 lane minima (ascending by lane) ----
  unsigned int v = mymin;
#pragma unroll
  for (int k = 2; k <= 64; k <<= 1) {
#pragma unroll
    for (int jj = k >> 1; jj >= 1; jj >>= 1) {
      unsigned int o = (unsigned int)__shfl_xor((int)v, jj);
      bool up = ((lane & k) == 0);
      bool low = ((lane & jj) == 0);
      bool tmin = (up == low);
      unsigned int mn = v < o ? v : o;
      unsigned int mx = v < o ? o : v;
      v = tmin ? mn : mx;
    }
  }

  // ---- pick threshold: idx-th smallest lane-min; ensure 16 <= cnt <= 128 ----
  int idx = 23, cnt = 0, tries = 0;
  unsigned int thr;
  for (;;) {
    thr = (unsigned int)__shfl((int)v, idx);
    cnt = 0;
    for (int it = 0; it < 64; ++it) {
      unsigned long long m = __ballot(S[(it << 6) + lane] <= thr);
      cnt += __popcll(m);
    }
    if ((cnt >= 16 && cnt <= 128) || ++tries >= 6) break;
    if (cnt < 16) idx = (idx + 12 > 63) ? 63 : idx + 12;
    else idx = (idx - 8 < 0) ? 0 : idx - 8;
  }

  // ---- collect survivors rank-ordered into LDS ----
  unsigned long long* SV = surv[wid];
  SV[lane] = ~0ull;
  SV[64 + lane] = ~0ull;
  int base = 0;
  for (int it = 0; it < 64; ++it) {
    int j = (it << 6) + lane;
    unsigned int s = S[j];
    bool hit = s <= thr;
    unsigned long long m = __ballot(hit);
    if (m) {
      int r = base + (int)__popcll(m & ((1ull << lane) - 1ull));
      if (hit && r < 128) SV[r] = ((unsigned long long)s << 32) | (unsigned int)j;
      base += (int)__popcll(m);
    }
  }
  unsigned long long k0 = SV[lane];
  unsigned long long k1 = SV[64 + lane];

  // ---- bitonic sort of 128 u64 keys over (slot, lane); e = slot*64 + lane ----
#pragma unroll
  for (int k = 2; k <= 128; k <<= 1) {
#pragma unroll
    for (int jj = k >> 1; jj >= 1; jj >>= 1) {
      if (jj == 64) {
        // cross-slot same-lane pair; only at k=128 -> ascending
        unsigned long long a = k0 < k1 ? k0 : k1;
        unsigned long long c = k0 < k1 ? k1 : k0;
        k0 = a; k1 = c;
      } else {
        {
          unsigned long long o = __shfl_xor(k0, jj);
          bool up = ((lane & k) == 0);            // e = lane: e&128 == 0 too
          bool low = ((lane & jj) == 0);
          bool tmin = (up == low);
          unsigned long long mn = k0 < o ? k0 : o;
          unsigned long long mx = k0 < o ? o : k0;
          k0 = tmin ? mn : mx;
        }
        {
          unsigned long long o = __shfl_xor(k1, jj);
          int e = 64 + lane;
          bool up = ((e & k) == 0);
          bool low = ((lane & jj) == 0);
          bool tmin = (up == low);
          unsigned long long mn = k1 < o ? k1 : o;
          unsigned long long mx = k1 < o ? o : k1;
          k1 = tmin ? mn : mx;
        }
      }
    }
  }

  int* op = (which ? idx2 : idx1) + (size_t)qi * KNB;
  if (lane < 16) op[lane] = (int)(k0 & 0xFFFFFFFFu);
}

// ---------------- transpose+convert feature [B,C,N] f32 -> [B*N][C] bf16 ----------------
__global__ __launch_bounds__(256) void conv_feat(const float* __restrict__ in,
                                                 unsigned short* __restrict__ out) {
  int bn = blockIdx.x;
  int b = bn >> 12, n = bn & 4095;
  int c = threadIdx.x;
  out[(size_t)bn * CH + c] = f2bf(in[((size_t)(b * CH + c)) * NPTS + n]);
}

// ---------------- convert weights to bf16 (keep [out][in] layout, pad W0 K to 544) --------
__global__ __launch_bounds__(544) void conv_w(const float* __restrict__ W0,
                                              const float* __restrict__ W1,
                                              const float* __restrict__ W2,
                                              unsigned short* __restrict__ W0b,
                                              unsigned short* __restrict__ W1b,
                                              unsigned short* __restrict__ W2b) {
  int r = blockIdx.x, c = threadIdx.x;
  if (r < 256) {
    W0b[r * KPAD0 + c] = (c < 515) ? f2bf(W0[r * 515 + c]) : (unsigned short)0;
  } else if (r < 512) {
    int rr = r - 256;
    if (c < 256) W1b[rr * 256 + c] = f2bf(W1[rr * 256 + c]);
  } else {
    int rr = r - 512;
    if (c < 256) W2b[rr * 256 + c] = f2bf(W2[rr * 256 + c]);
  }
}

// ---------------- per-row direction (bf16, padded to 32) + weightnet1 hidden (f32) --------
__global__ __launch_bounds__(256) void dir_kernel(
    const float* __restrict__ pc1, const float* __restrict__ pc2,
    const int* __restrict__ idx1,
    const float* __restrict__ wW1, const float* __restrict__ wb1,
    const float* __restrict__ wg, const float* __restrict__ wbe,
    const float* __restrict__ wmn, const float* __restrict__ wv,
    unsigned short* __restrict__ dirb, float* __restrict__ h1wn) {
  int m = blockIdx.x * 256 + threadIdx.x;  // 0..131071
  int bn = m >> 4;
  int b = bn >> 12, n = bn & 4095;
  int j = idx1[m];
  const float* p1 = pc1 + (size_t)b * 3 * NPTS;
  const float* p2 = pc2 + (size_t)b * 3 * NPTS;
  float d0 = p2[j] - p1[n];
  float d1 = p2[NPTS + j] - p1[NPTS + n];
  float d2 = p2[2 * NPTS + j] - p1[2 * NPTS + n];
  unsigned short row[32];
#pragma unroll
  for (int c = 0; c < 32; ++c) row[c] = 0;
  row[0] = f2bf(d0); row[1] = f2bf(d1); row[2] = f2bf(d2);
  float4* dp = (float4*)(dirb + (size_t)m * 32);
  const float4* sp = (const float4*)row;
  dp[0] = sp[0]; dp[1] = sp[1]; dp[2] = sp[2]; dp[3] = sp[3];
  float dv[3] = {d0, d1, d2};
#pragma unroll
  for (int jj = 0; jj < 8; ++jj) {
    float hv = wb1[jj];
#pragma unroll
    for (int c = 0; c < 3; ++c) hv = fmaf(dv[c], wW1[jj * 3 + c], hv);
    hv = wg[jj] * (hv - wmn[jj]) * (1.f / sqrtf(wv[jj] + BNEPS)) + wbe[jj];
    h1wn[(size_t)m * 8 + jj] = fmaxf(hv, 0.f);
  }
}

// ---------------- MFMA GEMM: [MTOT x K] @ [K x 256] -> leaky -> bf16 dst ----------------
template <int MODE>
__global__ __launch_bounds__(512) void gemm_kernel(
    const unsigned short* __restrict__ f1b, const unsigned short* __restrict__ f2b,
    const unsigned short* __restrict__ dirb, const int* __restrict__ idx1,
    const unsigned short* __restrict__ Asrc, const unsigned short* __restrict__ Wb,
    const float* __restrict__ bias, unsigned short* __restrict__ dst,
    int nchunks, int kpad) {
  __shared__ char smem[8192 + 16384];  // As [128][32] bf16, Bs [256][32] bf16 (quad-swizzled)
  const int tid = threadIdx.x;
  const int lane = tid & 63;
  const int w = tid >> 6;
  const int wm = w >> 2, wn = w & 3;
  const int m0 = blockIdx.x * BM;

  f32x4 acc[4][4];
#pragma unroll
  for (int nf = 0; nf < 4; ++nf) {
    float bv = bias[wn * 64 + nf * 16 + (lane & 15)];
#pragma unroll
    for (int mf = 0; mf < 4; ++mf) acc[mf][nf] = (f32x4){bv, bv, bv, bv};
  }

  const int ar = tid >> 2;                       // A row 0..127
  const int aql = (tid & 3) ^ ((ar >> 1) & 3);   // logical quad for this slot
  const int am = m0 + ar;
  const int anbr = (MODE == 0) ? (((am >> 16) << 12) + idx1[am]) : 0;
  const int br0 = tid >> 2;
  const int bq0 = (tid & 3) ^ ((br0 >> 1) & 3);
  const int br1 = (tid + 512) >> 2;
  const int bq1 = (tid & 3) ^ ((br1 >> 1) & 3);

  char* AsW = smem + (w << 10);
  char* BsW0 = smem + 8192 + (w << 10);
  char* BsW1 = smem + 8192 + 8192 + (w << 10);

  for (int kc = 0; kc < nchunks; ++kc) {
    __syncthreads();
    const unsigned short* ga;
    if (MODE == 0) {
      if (kc < 8)
        ga = f1b + ((am >> 4) << 8) + kc * 32 + aql * 8;
      else if (kc < 16)
        ga = f2b + ((size_t)anbr << 8) + (kc - 8) * 32 + aql * 8;
      else
        ga = dirb + ((size_t)am << 5) + aql * 8;
    } else {
      ga = Asrc + ((size_t)am << 8) + kc * 32 + aql * 8;
    }
    GLOAD_LDS16(ga, AsW);
    GLOAD_LDS16(Wb + (size_t)br0 * kpad + kc * 32 + bq0 * 8, BsW0);
    GLOAD_LDS16(Wb + (size_t)br1 * kpad + kc * 32 + bq1 * 8, BsW1);
    __syncthreads();

    bf16x8 af[4], bfr[4];
#pragma unroll
    for (int mf = 0; mf < 4; ++mf) {
      int r = wm * 64 + mf * 16 + (lane & 15);
      int off = r * 64 + ((((lane >> 4)) ^ ((r >> 1) & 3)) << 4);
      af[mf] = *(const bf16x8*)(smem + off);
    }
#pragma unroll
    for (int nf = 0; nf < 4; ++nf) {
      int r = wn * 64 + nf * 16 + (lane & 15);
      int off = r * 64 + ((((lane >> 4)) ^ ((r >> 1) & 3)) << 4);
      bfr[nf] = *(const bf16x8*)(smem + 8192 + off);
    }
#pragma unroll
    for (int mf = 0; mf < 4; ++mf)
#pragma unroll
      for (int nf = 0; nf < 4; ++nf)
        acc[mf][nf] = __builtin_amdgcn_mfma_f32_16x16x32_bf16(af[mf], bfr[nf], acc[mf][nf], 0, 0, 0);
  }

#pragma unroll
  for (int mf = 0; mf < 4; ++mf) {
#pragma unroll
    for (int nf = 0; nf < 4; ++nf) {
      int n = wn * 64 + nf * 16 + (lane & 15);
#pragma unroll
      for (int j = 0; j < 4; ++j) {
        int m = m0 + wm * 64 + mf * 16 + (lane >> 4) * 4 + j;
        float v = acc[mf][nf][j];
        v = v >= 0.f ? v : 0.1f * v;
        dst[(size_t)m * 256 + n] = f2bf(v);
      }
    }
  }
}

// ---------------- apply weightnet1, reduce over K -> out1 [8192][256] f32 ----------------
__global__ __launch_bounds__(256) void wreduce_kernel(
    const unsigned short* __restrict__ h2, const float* __restrict__ h1wn,
    const float* __restrict__ wW2, const float* __restrict__ wb2,
    float* __restrict__ out1) {
  __shared__ float g[KNB][8];
  int bn = blockIdx.x;
  int t = threadIdx.x;
  if (t < 128) g[t >> 3][t & 7] = h1wn[(size_t)(bn * KNB + (t >> 3)) * 8 + (t & 7)];
  float wrow[8];
#pragma unroll
  for (int jj = 0; jj < 8; ++jj) wrow[jj] = wW2[t * 8 + jj];
  float wb = wb2[t];
  __syncthreads();
  float o = 0.f;
#pragma unroll
  for (int k = 0; k < KNB; ++k) {
    float w1 = wb;
#pragma unroll
    for (int jj = 0; jj < 8; ++jj) w1 = fmaf(g[k][jj], wrow[jj], w1);
    float v = bf2f(h2[(size_t)(bn * KNB + k) * 256 + t]);
    o = fmaf(w1, v, o);
  }
  out1[(size_t)bn * 256 + t] = o;
}

// ---------------- stage 2: gather out1, weightnet2, K-reduce, write [B,C,N] ----------------
__global__ __launch_bounds__(256) void stage2_kernel(
    const float* __restrict__ out1, const float* __restrict__ pc1,
    const int* __restrict__ idx2,
    const float* __restrict__ wn_W1, const float* __restrict__ wn_b1,
    const float* __restrict__ wn_g, const float* __restrict__ wn_be,
    const float* __restrict__ wn_m, const float* __restrict__ wn_v,
    const float* __restrict__ wn_W2, const float* __restrict__ wn_b2,
    float* __restrict__ outp) {
  __shared__ float h1[KNB][8];
  __shared__ int nbrs[KNB];
  int bn = blockIdx.x;
  int b = bn >> 12, n = bn & 4095;
  int t = threadIdx.x;
  if (t < KNB) nbrs[t] = idx2[(size_t)bn * KNB + t];
  __syncthreads();
  if (t < 128) {
    int k = t >> 3, jj = t & 7;
    int j = nbrs[k];
    const float* p1 = pc1 + (size_t)b * 3 * NPTS;
    float d0 = p1[j] - p1[n];
    float d1 = p1[NPTS + j] - p1[NPTS + n];
    float d2v = p1[2 * NPTS + j] - p1[2 * NPTS + n];
    float hv = d0 * wn_W1[jj * 3] + d1 * wn_W1[jj * 3 + 1] + d2v * wn_W1[jj * 3 + 2] + wn_b1[jj];
    hv = wn_g[jj] * (hv - wn_m[jj]) * (1.f / sqrtf(wn_v[jj] + BNEPS)) + wn_be[jj];
    h1[k][jj] = fmaxf(hv, 0.f);
  }
  __syncthreads();
  float wrow[8];
#pragma unroll
  for (int jj = 0; jj < 8; ++jj) wrow[jj] = wn_W2[t * 8 + jj];
  float wb = wn_b2[t];
  float outv = 0.f;
#pragma unroll
  for (int k = 0; k < KNB; ++k) {
    float w2 = wb;
#pragma unroll
    for (int jj = 0; jj < 8; ++jj) w2 = fmaf(h1[k][jj], wrow[jj], w2);
    float v = out1[((size_t)(b * NPTS) + nbrs[k]) * CH + t];
    outv = fmaf(w2, v, outv);
  }
  outp[((size_t)(b * CH) + t) * NPTS + n] = outv;
}

extern "C" void kernel_launch(void* const* d_in, const int* in_sizes, int n_in,
                              void* d_out, int out_size, void* d_ws, size_t ws_size,
                              hipStream_t stream) {
  const float* pc1 = (const float*)d_in[0];
  const float* pc2 = (const float*)d_in[1];
  const float* f1 = (const float*)d_in[2];
  const float* f2 = (const float*)d_in[3];
  const float* W0 = (const float*)d_in[4];
  const float* b0 = (const float*)d_in[5];
  const float* W1 = (const float*)d_in[6];
  const float* b1 = (const float*)d_in[7];
  const float* W2 = (const float*)d_in[8];
  const float* b2 = (const float*)d_in[9];
  const float* wn1_W1 = (const float*)d_in[10];
  const float* wn1_b1 = (const float*)d_in[11];
  const float* wn1_g = (const float*)d_in[12];
  const float* wn1_be = (const float*)d_in[13];
  const float* wn1_m = (const float*)d_in[14];
  const float* wn1_v = (const float*)d_in[15];
  const float* wn1_W2 = (const float*)d_in[16];
  const float* wn1_b2 = (const float*)d_in[17];
  const float* wn2_W1 = (const float*)d_in[18];
  const float* wn2_b1 = (const float*)d_in[19];
  const float* wn2_g = (const float*)d_in[20];
  const float* wn2_be = (const float*)d_in[21];
  const float* wn2_m = (const float*)d_in[22];
  const float* wn2_v = (const float*)d_in[23];
  const float* wn2_W2 = (const float*)d_in[24];
  const float* wn2_b2 = (const float*)d_in[25];

  unsigned short* f1b = (unsigned short*)d_ws;
  unsigned short* f2b = f1b + (size_t)NB * NPTS * CH;
  unsigned short* W0b = f2b + (size_t)NB * NPTS * CH;
  unsigned short* W1b = W0b + (size_t)256 * KPAD0;
  unsigned short* W2b = W1b + (size_t)256 * 256;
  unsigned short* dirb = W2b + (size_t)256 * 256;
  unsigned short* h = dirb + (size_t)MTOT * 32;
  float* h1wn = (float*)(h + (size_t)MTOT * 256);
  float* out1 = h1wn + (size_t)MTOT * 8;
  int* idx1 = (int*)(out1 + (size_t)NB * NPTS * CH);
  int* idx2 = idx1 + (size_t)MTOT;
  float4* pk1 = (float4*)(idx2 + (size_t)MTOT);
  float4* pk2 = pk1 + (size_t)NB * NPTS;

  pack_pts<<<NB * NPTS / 256, 256, 0, stream>>>(pc1, pk1);
  pack_pts<<<NB * NPTS / 256, 256, 0, stream>>>(pc2, pk2);
  knn3_kernel<<<NB * NPTS * 2 / 4, 256, 0, stream>>>(pk1, pk2, idx1, idx2);
  conv_feat<<<NB * NPTS, 256, 0, stream>>>(f1, f1b);
  conv_feat<<<NB * NPTS, 256, 0, stream>>>(f2, f2b);
  conv_w<<<768, 544, 0, stream>>>(W0, W1, W2, W0b, W1b, W2b);
  dir_kernel<<<MTOT / 256, 256, 0, stream>>>(pc1, pc2, idx1, wn1_W1, wn1_b1, wn1_g,
                                             wn1_be, wn1_m, wn1_v, dirb, h1wn);
  gemm_kernel<0><<<MTOT / BM, 512, 0, stream>>>(
      f1b, f2b, dirb, idx1, (const unsigned short*)nullptr, W0b, b0, h, 17, KPAD0);
  gemm_kernel<1><<<MTOT / BM, 512, 0, stream>>>(
      f1b, f2b, dirb, idx1, h, W1b, b1, h, 8, 256);
  gemm_kernel<1><<<MTOT / BM, 512, 0, stream>>>(
      f1b, f2b, dirb, idx1, h, W2b, b2, h, 8, 256);
  wreduce_kernel<<<NB * NPTS, 256, 0, stream>>>(h, h1wn, wn1_W2, wn1_b2, out1);
  stage2_kernel<<<NB * NPTS, 256, 0, stream>>>(
      out1, pc1, idx2, wn2_W1, wn2_b1, wn2_g, wn2_be, wn2_m, wn2_v, wn2_W2, wn2_b2,
      (float*)d_out);
}